// Round 2
// baseline (258.971 us; speedup 1.0000x reference)
//
#include <hip/hip_runtime.h>
#include <hip/hip_bf16.h>

static constexpr int Hd = 768;    // H
static constexpr int H2 = 1536;   // 2H
static constexpr int Cn = 64;     // C (labels)

typedef __attribute__((ext_vector_type(8))) short short8;
typedef __attribute__((ext_vector_type(8))) _Float16 half8;
typedef __attribute__((ext_vector_type(4))) float f32x4;
typedef unsigned short us;

__device__ inline unsigned int f2bf2(float a, float b) {
    __hip_bfloat162 h = __float22bfloat162_rn(float2{a, b});
    return *reinterpret_cast<unsigned int*>(&h);
}

__device__ inline void split1(float x, us& h, us& l) {
    __hip_bfloat16 hb = __float2bfloat16(x);
    float hf = __bfloat162float(hb);
    __hip_bfloat16 lb_ = __float2bfloat16(x - hf);
    h = *reinterpret_cast<us*>(&hb);
    l = *reinterpret_cast<us*>(&lb_);
}

__device__ inline us f2b(float x) {
    __hip_bfloat16 b = __float2bfloat16(x);
    return *reinterpret_cast<us*>(&b);
}

__device__ inline us f2h(float x) {
    _Float16 h = (_Float16)x;
    return *reinterpret_cast<us*>(&h);
}

__device__ inline float b2f(us u) {
    __hip_bfloat16 b = *reinterpret_cast<__hip_bfloat16*>(&u);
    return __bfloat162float(b);
}

// packed fp16 elementwise product: 4x v_pk_mul_f16
__device__ inline short8 hmul8(short8 a, short8 b) {
    half8 x = __builtin_bit_cast(half8, a);
    half8 y = __builtin_bit_cast(half8, b);
    half8 r = x * y;
    return __builtin_bit_cast(short8, r);
}

__device__ inline void gload16(const void* g, void* l) {
    __builtin_amdgcn_global_load_lds(
        (const __attribute__((address_space(1))) unsigned int*)g,
        (__attribute__((address_space(3))) unsigned int*)l, 16, 0, 0);
}

// ---------------- init: widx = -1 ----------------
__global__ void k_init(int* widx, int Wd) {
    int i = blockIdx.x * 256 + threadIdx.x;
    if (i < Wd) widx[i] = -1;
}

__global__ void k_scatter(const int* __restrict__ wmask, int* widx, int L, int Wd) {
    int i = blockIdx.x * 256 + threadIdx.x;
    if (i < L) {
        int m = wmask[i];
        if (m > 0 && m <= Wd) atomicMax(&widx[m - 1], i);  // last token wins
    }
}

// build we directly as hi/lo bf16 split
__global__ void k_build_we_split(const float4* __restrict__ tok, const int* __restrict__ widx,
                                 us* __restrict__ weh, us* __restrict__ wel, int Wd) {
    int i = blockIdx.x * 256 + threadIdx.x;   // over Wd * 192
    if (i >= Wd * 192) return;
    int w = i / 192, c4 = i - w * 192;
    int idx = widx[w];
    float4 v = (idx >= 0) ? tok[idx * 192 + c4] : float4{0.f, 0.f, 0.f, 0.f};
    us hh[4], ll[4];
    split1(v.x, hh[0], ll[0]);
    split1(v.y, hh[1], ll[1]);
    split1(v.z, hh[2], ll[2]);
    split1(v.w, hh[3], ll[3]);
    size_t o = (size_t)w * Hd + c4 * 4;
    *(ushort4*)&weh[o] = ushort4{hh[0], hh[1], hh[2], hh[3]};
    *(ushort4*)&wel[o] = ushort4{ll[0], ll[1], ll[2], ll[3]};
}

// ---------- batched transpose + split: T[n][k]; fmt=0 bf16 hi/lo, fmt=1 fp16 (Th only) ----------
struct TSArgs {
    const float* src[5];
    us* th[5];
    us* tl[5];
    int ld[5];
    int N[5];
    int fmt[5];
};
__global__ __launch_bounds__(256)
void k_tsplit(TSArgs a) {
    __shared__ float tile[64][65];
    const int z = blockIdx.z;
    const int n0 = blockIdx.x * 64, k0 = blockIdx.y * 64;
    if (n0 >= a.N[z]) return;
    const float* W = a.src[z];
    const int ld = a.ld[z];
    for (int idx = threadIdx.x; idx < 4096; idx += 256) {
        int kk = idx >> 6, nn = idx & 63;
        tile[kk][nn] = W[(size_t)(k0 + kk) * ld + n0 + nn];
    }
    __syncthreads();
    us* Th = a.th[z];
    us* Tl = a.tl[z];
    const int fmt = a.fmt[z];
    for (int idx = threadIdx.x; idx < 4096; idx += 256) {
        int nn = idx >> 6, kk = idx & 63;
        size_t o = (size_t)(n0 + nn) * Hd + k0 + kk;
        if (fmt) {
            Th[o] = f2h(tile[kk][nn]);
        } else {
            us h, l;
            split1(tile[kk][nn], h, l);
            Th[o] = h;
            Tl[o] = l;
        }
    }
}

// ---------- row-major hi/lo split ----------
__global__ __launch_bounds__(256)
void k_split(const float* __restrict__ x, int lda, int cols,
             us* __restrict__ h, us* __restrict__ l, int n4) {
    int i = blockIdx.x * 256 + threadIdx.x;
    if (i >= n4) return;
    int c4 = cols >> 2;
    int row = i / c4, cc = (i - row * c4) * 4;
    float4 v = *(const float4*)&x[(size_t)row * lda + cc];
    us hh[4], ll[4];
    split1(v.x, hh[0], ll[0]);
    split1(v.y, hh[1], ll[1]);
    split1(v.z, hh[2], ll[2]);
    split1(v.w, hh[3], ll[3]);
    size_t o = (size_t)row * cols + cc;
    *(ushort4*)&h[o] = ushort4{hh[0], hh[1], hh[2], hh[3]};
    *(ushort4*)&l[o] = ushort4{ll[0], ll[1], ll[2], ll[3]};
}

// ---------- split-bf16 GEMM, LDS double-buffered, K-split partials (small Ms) ----------
__global__ __launch_bounds__(256)
void k_gemm2(const us* __restrict__ Ah, const us* __restrict__ Al,
             const us* __restrict__ BhT, const us* __restrict__ BlT,
             float* __restrict__ Cpart, int M, int N, int K) {
    __shared__ __align__(16) us S[2][4][64 * 32];
    const int tid = threadIdx.x, wave = tid >> 6, lane = tid & 63;
    const int quad = lane >> 4, l15 = lane & 15;
    const int wm = wave & 1, wn = wave >> 1;
    const int m0 = blockIdx.y * 64, n0 = blockIdx.x * 64;
    const int Ks = K / gridDim.z, kbeg = blockIdx.z * Ks, kend = kbeg + Ks;
    float* C = Cpart + (size_t)blockIdx.z * M * N;

    const int srow = wave * 16 + (lane >> 2), soff = (lane & 3) * 8;
    const size_t gaB = (size_t)(m0 + srow) * K + soff;
    const size_t gbB = (size_t)(n0 + srow) * K + soff;
    const int lo = wave * 16 * 32;

    f32x4 acc[2][2];
#pragma unroll
    for (int a = 0; a < 2; ++a)
#pragma unroll
        for (int b = 0; b < 2; ++b) acc[a][b] = (f32x4){0.f, 0.f, 0.f, 0.f};

    auto stage = [&](int p, int k0) {
        gload16(Ah + gaB + k0, &S[p][0][lo]);
        gload16(Al + gaB + k0, &S[p][1][lo]);
        gload16(BhT + gbB + k0, &S[p][2][lo]);
        gload16(BlT + gbB + k0, &S[p][3][lo]);
    };

    int p = 0;
    stage(0, kbeg);
    for (int k0 = kbeg; k0 < kend; k0 += 32) {
        __syncthreads();
        if (k0 + 32 < kend) stage(p ^ 1, k0 + 32);
        short8 ah[2], al[2], bh[2], bl[2];
#pragma unroll
        for (int mt = 0; mt < 2; ++mt) {
            int off = (wm * 32 + mt * 16 + l15) * 32 + quad * 8;
            ah[mt] = *(const short8*)&S[p][0][off];
            al[mt] = *(const short8*)&S[p][1][off];
        }
#pragma unroll
        for (int nt = 0; nt < 2; ++nt) {
            int off = (wn * 32 + nt * 16 + l15) * 32 + quad * 8;
            bh[nt] = *(const short8*)&S[p][2][off];
            bl[nt] = *(const short8*)&S[p][3][off];
        }
#pragma unroll
        for (int mt = 0; mt < 2; ++mt)
#pragma unroll
            for (int nt = 0; nt < 2; ++nt) {
                acc[mt][nt] = __builtin_amdgcn_mfma_f32_16x16x32_bf16(al[mt], bh[nt], acc[mt][nt], 0, 0, 0);
                acc[mt][nt] = __builtin_amdgcn_mfma_f32_16x16x32_bf16(ah[mt], bl[nt], acc[mt][nt], 0, 0, 0);
                acc[mt][nt] = __builtin_amdgcn_mfma_f32_16x16x32_bf16(ah[mt], bh[nt], acc[mt][nt], 0, 0, 0);
            }
        p ^= 1;
    }
#pragma unroll
    for (int mt = 0; mt < 2; ++mt)
#pragma unroll
        for (int nt = 0; nt < 2; ++nt) {
            int col = n0 + wn * 32 + nt * 16 + l15;
#pragma unroll
            for (int reg = 0; reg < 4; ++reg) {
                int row = m0 + wm * 32 + mt * 16 + quad * 4 + reg;
                C[(size_t)row * N + col] = acc[mt][nt][reg];
            }
        }
}

// ---------- split-bf16 GEMM, z=1, fused outputs (bias + f32 / hi-lo split / 16-bit) ----------
__global__ __launch_bounds__(256)
void k_gemm3(const us* __restrict__ Ah, const us* __restrict__ Al,
             const us* __restrict__ BhT, const us* __restrict__ BlT,
             const float* __restrict__ bias, float* __restrict__ outF,
             us* __restrict__ sh, us* __restrict__ sl, us* __restrict__ bh16,
             int fp16out, int scols, int N, int K) {
    __shared__ __align__(16) us S[2][4][64 * 32];
    const int tid = threadIdx.x, wave = tid >> 6, lane = tid & 63;
    const int quad = lane >> 4, l15 = lane & 15;
    const int wm = wave & 1, wn = wave >> 1;
    const int m0 = blockIdx.y * 64, n0 = blockIdx.x * 64;

    const int srow = wave * 16 + (lane >> 2), soff = (lane & 3) * 8;
    const size_t gaB = (size_t)(m0 + srow) * K + soff;
    const size_t gbB = (size_t)(n0 + srow) * K + soff;
    const int lo = wave * 16 * 32;

    f32x4 acc[2][2];
#pragma unroll
    for (int a = 0; a < 2; ++a)
#pragma unroll
        for (int b = 0; b < 2; ++b) acc[a][b] = (f32x4){0.f, 0.f, 0.f, 0.f};

    auto stage = [&](int p, int k0) {
        gload16(Ah + gaB + k0, &S[p][0][lo]);
        gload16(Al + gaB + k0, &S[p][1][lo]);
        gload16(BhT + gbB + k0, &S[p][2][lo]);
        gload16(BlT + gbB + k0, &S[p][3][lo]);
    };

    int p = 0;
    stage(0, 0);
    for (int k0 = 0; k0 < K; k0 += 32) {
        __syncthreads();
        if (k0 + 32 < K) stage(p ^ 1, k0 + 32);
        short8 ah[2], al[2], bh[2], bl[2];
#pragma unroll
        for (int mt = 0; mt < 2; ++mt) {
            int off = (wm * 32 + mt * 16 + l15) * 32 + quad * 8;
            ah[mt] = *(const short8*)&S[p][0][off];
            al[mt] = *(const short8*)&S[p][1][off];
        }
#pragma unroll
        for (int nt = 0; nt < 2; ++nt) {
            int off = (wn * 32 + nt * 16 + l15) * 32 + quad * 8;
            bh[nt] = *(const short8*)&S[p][2][off];
            bl[nt] = *(const short8*)&S[p][3][off];
        }
#pragma unroll
        for (int mt = 0; mt < 2; ++mt)
#pragma unroll
            for (int nt = 0; nt < 2; ++nt) {
                acc[mt][nt] = __builtin_amdgcn_mfma_f32_16x16x32_bf16(al[mt], bh[nt], acc[mt][nt], 0, 0, 0);
                acc[mt][nt] = __builtin_amdgcn_mfma_f32_16x16x32_bf16(ah[mt], bl[nt], acc[mt][nt], 0, 0, 0);
                acc[mt][nt] = __builtin_amdgcn_mfma_f32_16x16x32_bf16(ah[mt], bh[nt], acc[mt][nt], 0, 0, 0);
            }
        p ^= 1;
    }
#pragma unroll
    for (int mt = 0; mt < 2; ++mt)
#pragma unroll
        for (int nt = 0; nt < 2; ++nt) {
            int col = n0 + wn * 32 + nt * 16 + l15;
            float bb = bias ? bias[col] : 0.f;
#pragma unroll
            for (int reg = 0; reg < 4; ++reg) {
                int row = m0 + wm * 32 + mt * 16 + quad * 4 + reg;
                float v = acc[mt][nt][reg] + bb;
                if (outF) outF[(size_t)row * N + col] = v;
                if (sh) {
                    if (col < scols) {
                        us h, l;
                        split1(v, h, l);
                        size_t o = (size_t)row * scols + col;
                        sh[o] = h;
                        sl[o] = l;
                    } else if (bh16) {
                        bh16[(size_t)row * scols + (col - scols)] = fp16out ? f2h(v) : f2b(v);
                    }
                }
            }
        }
}

// ---------- reduce partials + bias; f32 out + hi/lo split (col<scols) + 16-bit (col>=scols) ----------
__global__ __launch_bounds__(256)
void k_reduce(const float* __restrict__ part, int S, int MN, int N,
              const float* __restrict__ bias, float* __restrict__ outF,
              us* __restrict__ sh, us* __restrict__ sl, int scols,
              us* __restrict__ bh16, int fp16out) {
    int i = blockIdx.x * 256 + threadIdx.x;
    if (i >= MN) return;
    float v = 0.f;
    for (int s = 0; s < S; ++s) v += part[(size_t)s * MN + i];
    int row = i / N, col = i - row * N;
    if (bias) v += bias[col];
    if (outF) outF[i] = v;
    if (col < scols) {
        if (sh) {
            us h, l;
            split1(v, h, l);
            size_t o = (size_t)row * scols + col;
            sh[o] = h;
            sl[o] = l;
        }
    } else if (bh16) {
        bh16[(size_t)row * scols + (col - scols)] = fp16out ? f2h(v) : f2b(v);
    }
}

// ---------------- P-GEMM v9: v8 + counted-vmcnt triple-buffer pipeline (T3/T4) + setprio (T5) ----------------
// Changes vs v8 (R1):
//  * Triple-buffered raw A/B tiles (16 KB each -> 48 KB). Main loop NEVER drains vmcnt:
//    waits vmcnt(4) (only the tile about to be read), raw s_barrier (no implicit drain),
//    then stages tile i+2 into the buffer consumed at iter i-1 (safe: every wave's iter
//    i-1 ds_reads returned before it reached barrier i, enforced by lgkmcnt before MFMA).
//    Last iteration peels to vmcnt(0).
//  * s_setprio(1) around the 32-MFMA cluster (2 independent blocks/CU at unsynced phases).
//  * sched_barrier(0) after the barrier pins ds_reads below it (rule #18).
__global__ __launch_bounds__(256, 2)
void k_mfma9(const us* __restrict__ t1b,   // (1024,768) fp16
             const us* __restrict__ W1ct,  // (768,768) fp16 [j][k]
             const us* __restrict__ lb1b,  // (64,768) fp16
             const float* __restrict__ Aw, // (1024,768) f32
             const float* __restrict__ Bc, // (64,768) f32 (includes b1)
             const float* __restrict__ W2, // (768,3) f32
             float* __restrict__ scr) {    // (6,1024,64,3) f32 partials
    __shared__ __align__(16) us As[3][4096];   // [q][row][8] chunk-major, 8 KB per buf
    __shared__ __align__(16) us Bs[3][4096];
    __shared__ __align__(16) us lbs[2][Hd];    // lb1 rows for the 2 labels
    __shared__ float sred[2 * 128 * 3];

    const int tid = threadIdx.x, wave = tid >> 6, lane = tid & 63;
    const int quad = lane >> 4, l15 = lane & 15;
    const int wm = wave & 1, wn = wave >> 1;

    // L2-locality decode: b = xcd + 8*(jx*32 + cp); my = xcd
    const int b = blockIdx.x;
    const int xcd = b & 7, slot = b >> 3;    // slot 0..191
    const int jx = slot >> 5;                // 0..5
    const int cp = slot & 31;                // 0..31 (varies fastest)
    const int c0 = cp * 2;
    const int jt = jx * 128, m0 = xcd * 128;

    for (int i = tid; i < 2 * 128 * 3; i += 256) sred[i] = 0.f;
    if (tid < 192) {                          // stage lb1 rows c0,c0+1 (3 KB)
        int cc = tid / 96, o = (tid - cc * 96) * 8;
        *(short8*)&lbs[cc][o] = *(const short8*)&lb1b[(size_t)(c0 + cc) * Hd + o];
    }

    // staging map: wave issues chunks i=wave and i=wave+4; i -> (q=i>>1, rhalf=i&1)
    // LDS inst i covers bytes [i*1024, i*1024+1024) = (q, rows rhalf*64 .. +63), lane -> row
    const int srow = (wave & 1) * 64 + lane;
    const int skq = (wave >> 1) * 8;          // k offset of chunk q within the 32-k step
    const us* gA = W1ct + (size_t)(jt + srow) * Hd + skq;
    const us* gB = t1b + (size_t)(m0 + srow) * Hd + skq;

    f32x4 acc0[4][4], acc1[4][4];
#pragma unroll
    for (int mt = 0; mt < 4; ++mt)
#pragma unroll
        for (int nt = 0; nt < 4; ++nt) {
            acc0[mt][nt] = (f32x4){0.f, 0.f, 0.f, 0.f};
            acc1[mt][nt] = (f32x4){0.f, 0.f, 0.f, 0.f};
        }

    auto stage = [&](int p, int k0) {
        gload16(gA + k0,      &As[p][wave * 512]);
        gload16(gA + k0 + 16, &As[p][(wave + 4) * 512]);
        gload16(gB + k0,      &Bs[p][wave * 512]);
        gload16(gB + k0 + 16, &Bs[p][(wave + 4) * 512]);
    };

    // fragment read bases: element (q, row) at us-index q*1024 + row*8
    const int rbA = quad * 1024 + (wm * 64 + l15) * 8;
    const int rbB = quad * 1024 + (wn * 64 + l15) * 8;

    // lbs/sred writes must be visible to all waves before lv reads; nothing in
    // the VMEM queue yet, so this (draining) barrier is free.
    __syncthreads();

    stage(0, 0);         // 4 loads in flight
    stage(1, 32);        // 8 loads in flight
    int p = 0;
    for (int k0 = 0; k0 < Hd; k0 += 32) {
        // wait only for the tile we're about to read; keep the rest in flight
        if (k0 + 32 < Hd) asm volatile("s_waitcnt vmcnt(4)" ::: "memory");
        else              asm volatile("s_waitcnt vmcnt(0)" ::: "memory");
        __builtin_amdgcn_s_barrier();
        __builtin_amdgcn_sched_barrier(0);
        // stage tile i+2 into the buffer consumed at iter i-1 (post-barrier => WAR-safe)
        if (k0 + 64 < Hd) {
            int nb = p + 2; if (nb >= 3) nb -= 3;
            stage(nb, k0 + 64);
        }
        short8 af[4], bf[4];
#pragma unroll
        for (int mt = 0; mt < 4; ++mt) af[mt] = *(const short8*)&As[p][rbA + mt * 128];
#pragma unroll
        for (int nt = 0; nt < 4; ++nt) bf[nt] = *(const short8*)&Bs[p][rbB + nt * 128];
        short8 lv0 = *(const short8*)&lbs[0][k0 + quad * 8];   // broadcast within quad
        short8 lv1 = *(const short8*)&lbs[1][k0 + quad * 8];
        __builtin_amdgcn_s_setprio(1);
#pragma unroll
        for (int mt = 0; mt < 4; ++mt) {
            short8 a0 = hmul8(af[mt], lv0);
            short8 a1 = hmul8(af[mt], lv1);
#pragma unroll
            for (int nt = 0; nt < 4; ++nt) {
                acc0[mt][nt] = __builtin_amdgcn_mfma_f32_16x16x32_f16(
                    __builtin_bit_cast(half8, a0),
                    __builtin_bit_cast(half8, bf[nt]), acc0[mt][nt], 0, 0, 0);
                acc1[mt][nt] = __builtin_amdgcn_mfma_f32_16x16x32_f16(
                    __builtin_bit_cast(half8, a1),
                    __builtin_bit_cast(half8, bf[nt]), acc1[mt][nt], 0, 0, 0);
            }
        }
        __builtin_amdgcn_s_setprio(0);
        p = (p + 1 < 3) ? p + 1 : 0;
    }

    // ---- epilogue: per c: h = relu(P + Aw + Bc); sacc[w][r] += h*W2[j][r] ----
    // j = jt + wm*64 + mt*16 + quad*4 + reg ; w = m0 + wn*64 + nt*16 + l15
    float bcv0[4][4], bcv1[4][4], w2v[4][4][3];
#pragma unroll
    for (int mt = 0; mt < 4; ++mt) {
        const int jb = jt + wm * 64 + mt * 16 + quad * 4;
        float4 b4 = *(const float4*)&Bc[(size_t)c0 * Hd + jb];
        bcv0[mt][0] = b4.x; bcv0[mt][1] = b4.y; bcv0[mt][2] = b4.z; bcv0[mt][3] = b4.w;
        float4 b5 = *(const float4*)&Bc[(size_t)(c0 + 1) * Hd + jb];
        bcv1[mt][0] = b5.x; bcv1[mt][1] = b5.y; bcv1[mt][2] = b5.z; bcv1[mt][3] = b5.w;
#pragma unroll
        for (int reg = 0; reg < 4; ++reg)
#pragma unroll
            for (int r = 0; r < 3; ++r) w2v[mt][reg][r] = W2[(jb + reg) * 3 + r];
    }

    auto reduce_c = [&](const f32x4 (&ac)[4][4], const float (&bcv)[4][4], int cc) {
#pragma unroll
        for (int nt = 0; nt < 4; ++nt) {
            const int w = m0 + wn * 64 + nt * 16 + l15;
            const float* awp = Aw + (size_t)w * Hd + jt + wm * 64;
            float s0 = 0.f, s1 = 0.f, s2 = 0.f;
#pragma unroll
            for (int mt = 0; mt < 4; ++mt) {
                float4 a4 = *(const float4*)&awp[mt * 16 + quad * 4];
                float av[4] = {a4.x, a4.y, a4.z, a4.w};
#pragma unroll
                for (int reg = 0; reg < 4; ++reg) {
                    float h = ac[mt][nt][reg] + av[reg] + bcv[mt][reg];
                    h = h > 0.f ? h : 0.f;
                    s0 += h * w2v[mt][reg][0];
                    s1 += h * w2v[mt][reg][1];
                    s2 += h * w2v[mt][reg][2];
                }
            }
            s0 += __shfl_xor(s0, 16); s0 += __shfl_xor(s0, 32);
            s1 += __shfl_xor(s1, 16); s1 += __shfl_xor(s1, 32);
            s2 += __shfl_xor(s2, 16); s2 += __shfl_xor(s2, 32);
            if (quad == 0) {
                const int wl = wn * 64 + nt * 16 + l15;
                atomicAdd(&sred[cc * 384 + wl * 3 + 0], s0);   // LDS, 2-way (wm)
                atomicAdd(&sred[cc * 384 + wl * 3 + 1], s1);
                atomicAdd(&sred[cc * 384 + wl * 3 + 2], s2);
            }
        }
    };
    reduce_c(acc0, bcv0, 0);
    reduce_c(acc1, bcv1, 1);
    __syncthreads();

    // non-atomic store to per-jx scratch slot (disjoint across blocks)
    float* slab = scr + ((size_t)jx * 1024 * Cn + (size_t)m0 * Cn) * 3;
    for (int i = tid; i < 2 * 128 * 3; i += 256) {
        int cc = i / 384, j = i - cc * 384;
        int wl = j / 3, r = j - wl * 3;
        slab[((size_t)wl * Cn + (c0 + cc)) * 3 + r] = sred[i];
    }
}

// ---------- final: out = b2 + sum_jx scr[jx] ----------
__global__ __launch_bounds__(256)
void k_scores(const float* __restrict__ scr, const float* __restrict__ b2,
              float* __restrict__ out, int n) {
    int i = blockIdx.x * 256 + threadIdx.x;
    if (i >= n) return;
    float v = b2[i % 3];
#pragma unroll
    for (int s = 0; s < 6; ++s) v += scr[(size_t)s * n + i];
    out[i] = v;
}

extern "C" void kernel_launch(void* const* d_in, const int* in_sizes, int n_in,
                              void* d_out, int out_size, void* d_ws, size_t ws_size,
                              hipStream_t stream) {
    const float* tok    = (const float*)d_in[0];
    const int*   wmask  = (const int*)d_in[1];
    const float* labe   = (const float*)d_in[3];
    const float* W_tok  = (const float*)d_in[4];
    const float* b_tok  = (const float*)d_in[5];
    const float* W_lab  = (const float*)d_in[6];
    const float* b_lab  = (const float*)d_in[7];
    const float* W1     = (const float*)d_in[8];
    const float* b1     = (const float*)d_in[9];
    const float* W2     = (const float*)d_in[10];
    const float* b2     = (const float*)d_in[11];
    float* out = (float*)d_out;

    const int L  = in_sizes[1];
    const int Wd = out_size / (Cn * 3);   // 1024

    char* ws = (char*)d_ws;
    size_t off = 0;
    auto alloc = [&](size_t bytes) { char* p = ws + off; off += (bytes + 255) & ~(size_t)255; return p; };
    // ---- persistent region ----
    int*   widx  = (int*)alloc(4096);
    float* Abuf  = (float*)alloc((size_t)Wd * Hd * 4);
    float* Bbuf  = (float*)alloc((size_t)Cn * Hd * 4);
    us* W1ct  = (us*)alloc((size_t)Hd * Hd * 2);   // fp16
    us* W1cl  = (us*)alloc((size_t)Hd * Hd * 2);   // unused
    us* t1b   = (us*)alloc((size_t)Wd * Hd * 2);   // fp16
    us* lb1b  = (us*)alloc((size_t)Cn * Hd * 2);   // fp16
    float* scr = (float*)alloc((size_t)6 * Wd * Cn * 3 * 4);   // 4.72 MB partials
    // ---- scratch region ----
    us* WtTh  = (us*)alloc((size_t)H2 * Hd * 2);
    us* WtTl  = (us*)alloc((size_t)H2 * Hd * 2);
    us* WlTh  = (us*)alloc((size_t)H2 * Hd * 2);
    us* WlTl  = (us*)alloc((size_t)H2 * Hd * 2);
    us* W1aTh = (us*)alloc((size_t)Hd * Hd * 2);
    us* W1aTl = (us*)alloc((size_t)Hd * Hd * 2);
    us* W1bTh = (us*)alloc((size_t)Hd * Hd * 2);
    us* W1bTl = (us*)alloc((size_t)Hd * Hd * 2);
    us* weh   = (us*)alloc((size_t)Wd * Hd * 2);
    us* wel   = (us*)alloc((size_t)Wd * Hd * 2);
    us* lah   = (us*)alloc((size_t)Cn * Hd * 2);
    us* lal   = (us*)alloc((size_t)Cn * Hd * 2);
    us* t0h   = (us*)alloc((size_t)Wd * Hd * 2);
    us* t0l   = (us*)alloc((size_t)Wd * Hd * 2);
    us* lb0h  = (us*)alloc((size_t)Cn * Hd * 2);
    us* lb0l  = (us*)alloc((size_t)Cn * Hd * 2);
    float* part = (float*)alloc((size_t)8 * Cn * H2 * 4);

    // 1) init + scatter + we split
    k_init<<<(Wd + 255) / 256, 256, 0, stream>>>(widx, Wd);
    k_scatter<<<(L + 255) / 256, 256, 0, stream>>>(wmask, widx, L, Wd);
    k_build_we_split<<<(Wd * 192 + 255) / 256, 256, 0, stream>>>((const float4*)tok, widx, weh, wel, Wd);

    // 2) batched weight transpose+split (W1c -> fp16)
    TSArgs ts;
    ts.src[0] = W_tok;  ts.th[0] = WtTh;  ts.tl[0] = WtTl;  ts.ld[0] = H2; ts.N[0] = H2; ts.fmt[0] = 0;
    ts.src[1] = W_lab;  ts.th[1] = WlTh;  ts.tl[1] = WlTl;  ts.ld[1] = H2; ts.N[1] = H2; ts.fmt[1] = 0;
    ts.src[2] = W1;                         ts.th[2] = W1aTh; ts.tl[2] = W1aTl; ts.ld[2] = Hd; ts.N[2] = Hd; ts.fmt[2] = 0;
    ts.src[3] = W1 + (size_t)Hd * Hd;       ts.th[3] = W1bTh; ts.tl[3] = W1bTl; ts.ld[3] = Hd; ts.N[3] = Hd; ts.fmt[3] = 0;
    ts.src[4] = W1 + (size_t)2 * Hd * Hd;   ts.th[4] = W1ct;  ts.tl[4] = W1cl;  ts.ld[4] = Hd; ts.N[4] = Hd; ts.fmt[4] = 1;
    k_tsplit<<<dim3(H2 / 64, Hd / 64, 5), 256, 0, stream>>>(ts);

    // 3) label emb split
    k_split<<<(Cn * Hd / 4 + 255) / 256, 256, 0, stream>>>(labe, Hd, Hd, lah, lal, Cn * Hd / 4);

    // 4) t = we @ W_tok + b_tok -> fused t0 hi/lo + t1b fp16
    k_gemm3<<<dim3(H2 / 64, Wd / 64), 256, 0, stream>>>(weh, wel, WtTh, WtTl, b_tok,
                                                        nullptr, t0h, t0l, t1b, 1, Hd, H2, Hd);

    // 5) lb = labe @ W_lab + b_lab (64x1536), z=8 -> reduce (lb0 split + lb1b fp16)
    k_gemm2<<<dim3(H2 / 64, 1, 8), 256, 0, stream>>>(lah, lal, WlTh, WlTl, part, Cn, H2, Hd);
    k_reduce<<<(Cn * H2 + 255) / 256, 256, 0, stream>>>(part, 8, Cn * H2, H2, b_lab, nullptr, lb0h, lb0l, Hd, lb1b, 1);

    // 6) Aw = t0 @ W1a (1024x768) -> fused f32 write
    k_gemm3<<<dim3(Hd / 64, Wd / 64), 256, 0, stream>>>(t0h, t0l, W1aTh, W1aTl, nullptr,
                                                        Abuf, nullptr, nullptr, nullptr, 0, 0, Hd, Hd);

    // 7) Bc = lb0 @ W1b + b1 (64x768), z=8 -> reduce
    k_gemm2<<<dim3(Hd / 64, 1, 8), 256, 0, stream>>>(lb0h, lb0l, W1bTh, W1bTl, part, Cn, Hd, Hd);
    k_reduce<<<(Cn * Hd + 255) / 256, 256, 0, stream>>>(part, 8, Cn * Hd, Hd, b1, Bbuf, nullptr, nullptr, Hd, nullptr, 0);

    // 8) fused fp16 P-GEMM v9 (counted-vmcnt triple-buffer pipeline) -> scratch
    k_mfma9<<<1536, 256, 0, stream>>>(t1b, W1ct, lb1b, Abuf, Bbuf, W2, scr);

    // 9) out = b2 + sum_jx scr
    k_scores<<<(Wd * Cn * 3 + 255) / 256, 256, 0, stream>>>(scr, b2, out, Wd * Cn * 3);
}

// Round 3
// 250.402 us; speedup vs baseline: 1.0342x; 1.0342x over previous
//
#include <hip/hip_runtime.h>
#include <hip/hip_bf16.h>

static constexpr int Hd = 768;    // H
static constexpr int H2 = 1536;   // 2H
static constexpr int Cn = 64;     // C (labels)

typedef __attribute__((ext_vector_type(8))) short short8;
typedef __attribute__((ext_vector_type(8))) _Float16 half8;
typedef __attribute__((ext_vector_type(4))) float f32x4;
typedef unsigned short us;

__device__ inline unsigned int f2bf2(float a, float b) {
    __hip_bfloat162 h = __float22bfloat162_rn(float2{a, b});
    return *reinterpret_cast<unsigned int*>(&h);
}

__device__ inline void split1(float x, us& h, us& l) {
    __hip_bfloat16 hb = __float2bfloat16(x);
    float hf = __bfloat162float(hb);
    __hip_bfloat16 lb_ = __float2bfloat16(x - hf);
    h = *reinterpret_cast<us*>(&hb);
    l = *reinterpret_cast<us*>(&lb_);
}

__device__ inline us f2b(float x) {
    __hip_bfloat16 b = __float2bfloat16(x);
    return *reinterpret_cast<us*>(&b);
}

__device__ inline us f2h(float x) {
    _Float16 h = (_Float16)x;
    return *reinterpret_cast<us*>(&h);
}

__device__ inline float b2f(us u) {
    __hip_bfloat16 b = *reinterpret_cast<__hip_bfloat16*>(&u);
    return __bfloat162float(b);
}

// packed fp16 elementwise product: 4x v_pk_mul_f16
__device__ inline short8 hmul8(short8 a, short8 b) {
    half8 x = __builtin_bit_cast(half8, a);
    half8 y = __builtin_bit_cast(half8, b);
    half8 r = x * y;
    return __builtin_bit_cast(short8, r);
}

__device__ inline void gload16(const void* g, void* l) {
    __builtin_amdgcn_global_load_lds(
        (const __attribute__((address_space(1))) unsigned int*)g,
        (__attribute__((address_space(3))) unsigned int*)l, 16, 0, 0);
}

// ---------------- init: widx = -1 ----------------
__global__ void k_init(int* widx, int Wd) {
    int i = blockIdx.x * 256 + threadIdx.x;
    if (i < Wd) widx[i] = -1;
}

__global__ void k_scatter(const int* __restrict__ wmask, int* widx, int L, int Wd) {
    int i = blockIdx.x * 256 + threadIdx.x;
    if (i < L) {
        int m = wmask[i];
        if (m > 0 && m <= Wd) atomicMax(&widx[m - 1], i);  // last token wins
    }
}

// build we directly as hi/lo bf16 split
__global__ void k_build_we_split(const float4* __restrict__ tok, const int* __restrict__ widx,
                                 us* __restrict__ weh, us* __restrict__ wel, int Wd) {
    int i = blockIdx.x * 256 + threadIdx.x;   // over Wd * 192
    if (i >= Wd * 192) return;
    int w = i / 192, c4 = i - w * 192;
    int idx = widx[w];
    float4 v = (idx >= 0) ? tok[idx * 192 + c4] : float4{0.f, 0.f, 0.f, 0.f};
    us hh[4], ll[4];
    split1(v.x, hh[0], ll[0]);
    split1(v.y, hh[1], ll[1]);
    split1(v.z, hh[2], ll[2]);
    split1(v.w, hh[3], ll[3]);
    size_t o = (size_t)w * Hd + c4 * 4;
    *(ushort4*)&weh[o] = ushort4{hh[0], hh[1], hh[2], hh[3]};
    *(ushort4*)&wel[o] = ushort4{ll[0], ll[1], ll[2], ll[3]};
}

// ---------- batched transpose + split: T[n][k]; fmt=0 bf16 hi/lo, fmt=1 fp16 (Th only) ----------
struct TSArgs {
    const float* src[5];
    us* th[5];
    us* tl[5];
    int ld[5];
    int N[5];
    int fmt[5];
};
__global__ __launch_bounds__(256)
void k_tsplit(TSArgs a) {
    __shared__ float tile[64][65];
    const int z = blockIdx.z;
    const int n0 = blockIdx.x * 64, k0 = blockIdx.y * 64;
    if (n0 >= a.N[z]) return;
    const float* W = a.src[z];
    const int ld = a.ld[z];
    for (int idx = threadIdx.x; idx < 4096; idx += 256) {
        int kk = idx >> 6, nn = idx & 63;
        tile[kk][nn] = W[(size_t)(k0 + kk) * ld + n0 + nn];
    }
    __syncthreads();
    us* Th = a.th[z];
    us* Tl = a.tl[z];
    const int fmt = a.fmt[z];
    for (int idx = threadIdx.x; idx < 4096; idx += 256) {
        int nn = idx >> 6, kk = idx & 63;
        size_t o = (size_t)(n0 + nn) * Hd + k0 + kk;
        if (fmt) {
            Th[o] = f2h(tile[kk][nn]);
        } else {
            us h, l;
            split1(tile[kk][nn], h, l);
            Th[o] = h;
            Tl[o] = l;
        }
    }
}

// ---------- row-major hi/lo split ----------
__global__ __launch_bounds__(256)
void k_split(const float* __restrict__ x, int lda, int cols,
             us* __restrict__ h, us* __restrict__ l, int n4) {
    int i = blockIdx.x * 256 + threadIdx.x;
    if (i >= n4) return;
    int c4 = cols >> 2;
    int row = i / c4, cc = (i - row * c4) * 4;
    float4 v = *(const float4*)&x[(size_t)row * lda + cc];
    us hh[4], ll[4];
    split1(v.x, hh[0], ll[0]);
    split1(v.y, hh[1], ll[1]);
    split1(v.z, hh[2], ll[2]);
    split1(v.w, hh[3], ll[3]);
    size_t o = (size_t)row * cols + cc;
    *(ushort4*)&h[o] = ushort4{hh[0], hh[1], hh[2], hh[3]};
    *(ushort4*)&l[o] = ushort4{ll[0], ll[1], ll[2], ll[3]};
}

// ---------- split-bf16 GEMM, LDS double-buffered, K-split partials (small Ms) ----------
__global__ __launch_bounds__(256)
void k_gemm2(const us* __restrict__ Ah, const us* __restrict__ Al,
             const us* __restrict__ BhT, const us* __restrict__ BlT,
             float* __restrict__ Cpart, int M, int N, int K) {
    __shared__ __align__(16) us S[2][4][64 * 32];
    const int tid = threadIdx.x, wave = tid >> 6, lane = tid & 63;
    const int quad = lane >> 4, l15 = lane & 15;
    const int wm = wave & 1, wn = wave >> 1;
    const int m0 = blockIdx.y * 64, n0 = blockIdx.x * 64;
    const int Ks = K / gridDim.z, kbeg = blockIdx.z * Ks, kend = kbeg + Ks;
    float* C = Cpart + (size_t)blockIdx.z * M * N;

    const int srow = wave * 16 + (lane >> 2), soff = (lane & 3) * 8;
    const size_t gaB = (size_t)(m0 + srow) * K + soff;
    const size_t gbB = (size_t)(n0 + srow) * K + soff;
    const int lo = wave * 16 * 32;

    f32x4 acc[2][2];
#pragma unroll
    for (int a = 0; a < 2; ++a)
#pragma unroll
        for (int b = 0; b < 2; ++b) acc[a][b] = (f32x4){0.f, 0.f, 0.f, 0.f};

    auto stage = [&](int p, int k0) {
        gload16(Ah + gaB + k0, &S[p][0][lo]);
        gload16(Al + gaB + k0, &S[p][1][lo]);
        gload16(BhT + gbB + k0, &S[p][2][lo]);
        gload16(BlT + gbB + k0, &S[p][3][lo]);
    };

    int p = 0;
    stage(0, kbeg);
    for (int k0 = kbeg; k0 < kend; k0 += 32) {
        __syncthreads();
        if (k0 + 32 < kend) stage(p ^ 1, k0 + 32);
        short8 ah[2], al[2], bh[2], bl[2];
#pragma unroll
        for (int mt = 0; mt < 2; ++mt) {
            int off = (wm * 32 + mt * 16 + l15) * 32 + quad * 8;
            ah[mt] = *(const short8*)&S[p][0][off];
            al[mt] = *(const short8*)&S[p][1][off];
        }
#pragma unroll
        for (int nt = 0; nt < 2; ++nt) {
            int off = (wn * 32 + nt * 16 + l15) * 32 + quad * 8;
            bh[nt] = *(const short8*)&S[p][2][off];
            bl[nt] = *(const short8*)&S[p][3][off];
        }
#pragma unroll
        for (int mt = 0; mt < 2; ++mt)
#pragma unroll
            for (int nt = 0; nt < 2; ++nt) {
                acc[mt][nt] = __builtin_amdgcn_mfma_f32_16x16x32_bf16(al[mt], bh[nt], acc[mt][nt], 0, 0, 0);
                acc[mt][nt] = __builtin_amdgcn_mfma_f32_16x16x32_bf16(ah[mt], bl[nt], acc[mt][nt], 0, 0, 0);
                acc[mt][nt] = __builtin_amdgcn_mfma_f32_16x16x32_bf16(ah[mt], bh[nt], acc[mt][nt], 0, 0, 0);
            }
        p ^= 1;
    }
#pragma unroll
    for (int mt = 0; mt < 2; ++mt)
#pragma unroll
        for (int nt = 0; nt < 2; ++nt) {
            int col = n0 + wn * 32 + nt * 16 + l15;
#pragma unroll
            for (int reg = 0; reg < 4; ++reg) {
                int row = m0 + wm * 32 + mt * 16 + quad * 4 + reg;
                C[(size_t)row * N + col] = acc[mt][nt][reg];
            }
        }
}

// ---------- split-bf16 GEMM, z=1, fused outputs (bias + f32 / hi-lo split / 16-bit) ----------
__global__ __launch_bounds__(256)
void k_gemm3(const us* __restrict__ Ah, const us* __restrict__ Al,
             const us* __restrict__ BhT, const us* __restrict__ BlT,
             const float* __restrict__ bias, float* __restrict__ outF,
             us* __restrict__ sh, us* __restrict__ sl, us* __restrict__ bh16,
             int fp16out, int scols, int N, int K) {
    __shared__ __align__(16) us S[2][4][64 * 32];
    const int tid = threadIdx.x, wave = tid >> 6, lane = tid & 63;
    const int quad = lane >> 4, l15 = lane & 15;
    const int wm = wave & 1, wn = wave >> 1;
    const int m0 = blockIdx.y * 64, n0 = blockIdx.x * 64;

    const int srow = wave * 16 + (lane >> 2), soff = (lane & 3) * 8;
    const size_t gaB = (size_t)(m0 + srow) * K + soff;
    const size_t gbB = (size_t)(n0 + srow) * K + soff;
    const int lo = wave * 16 * 32;

    f32x4 acc[2][2];
#pragma unroll
    for (int a = 0; a < 2; ++a)
#pragma unroll
        for (int b = 0; b < 2; ++b) acc[a][b] = (f32x4){0.f, 0.f, 0.f, 0.f};

    auto stage = [&](int p, int k0) {
        gload16(Ah + gaB + k0, &S[p][0][lo]);
        gload16(Al + gaB + k0, &S[p][1][lo]);
        gload16(BhT + gbB + k0, &S[p][2][lo]);
        gload16(BlT + gbB + k0, &S[p][3][lo]);
    };

    int p = 0;
    stage(0, 0);
    for (int k0 = 0; k0 < K; k0 += 32) {
        __syncthreads();
        if (k0 + 32 < K) stage(p ^ 1, k0 + 32);
        short8 ah[2], al[2], bh[2], bl[2];
#pragma unroll
        for (int mt = 0; mt < 2; ++mt) {
            int off = (wm * 32 + mt * 16 + l15) * 32 + quad * 8;
            ah[mt] = *(const short8*)&S[p][0][off];
            al[mt] = *(const short8*)&S[p][1][off];
        }
#pragma unroll
        for (int nt = 0; nt < 2; ++nt) {
            int off = (wn * 32 + nt * 16 + l15) * 32 + quad * 8;
            bh[nt] = *(const short8*)&S[p][2][off];
            bl[nt] = *(const short8*)&S[p][3][off];
        }
#pragma unroll
        for (int mt = 0; mt < 2; ++mt)
#pragma unroll
            for (int nt = 0; nt < 2; ++nt) {
                acc[mt][nt] = __builtin_amdgcn_mfma_f32_16x16x32_bf16(al[mt], bh[nt], acc[mt][nt], 0, 0, 0);
                acc[mt][nt] = __builtin_amdgcn_mfma_f32_16x16x32_bf16(ah[mt], bl[nt], acc[mt][nt], 0, 0, 0);
                acc[mt][nt] = __builtin_amdgcn_mfma_f32_16x16x32_bf16(ah[mt], bh[nt], acc[mt][nt], 0, 0, 0);
            }
        p ^= 1;
    }
#pragma unroll
    for (int mt = 0; mt < 2; ++mt)
#pragma unroll
        for (int nt = 0; nt < 2; ++nt) {
            int col = n0 + wn * 32 + nt * 16 + l15;
            float bb = bias ? bias[col] : 0.f;
#pragma unroll
            for (int reg = 0; reg < 4; ++reg) {
                int row = m0 + wm * 32 + mt * 16 + quad * 4 + reg;
                float v = acc[mt][nt][reg] + bb;
                if (outF) outF[(size_t)row * N + col] = v;
                if (sh) {
                    if (col < scols) {
                        us h, l;
                        split1(v, h, l);
                        size_t o = (size_t)row * scols + col;
                        sh[o] = h;
                        sl[o] = l;
                    } else if (bh16) {
                        bh16[(size_t)row * scols + (col - scols)] = fp16out ? f2h(v) : f2b(v);
                    }
                }
            }
        }
}

// ---------- reduce partials + bias; f32 out + hi/lo split (col<scols) + 16-bit (col>=scols) ----------
__global__ __launch_bounds__(256)
void k_reduce(const float* __restrict__ part, int S, int MN, int N,
              const float* __restrict__ bias, float* __restrict__ outF,
              us* __restrict__ sh, us* __restrict__ sl, int scols,
              us* __restrict__ bh16, int fp16out) {
    int i = blockIdx.x * 256 + threadIdx.x;
    if (i >= MN) return;
    float v = 0.f;
    for (int s = 0; s < S; ++s) v += part[(size_t)s * MN + i];
    int row = i / N, col = i - row * N;
    if (bias) v += bias[col];
    if (outF) outF[i] = v;
    if (col < scols) {
        if (sh) {
            us h, l;
            split1(v, h, l);
            size_t o = (size_t)row * scols + col;
            sh[o] = h;
            sl[o] = l;
        }
    } else if (bh16) {
        bh16[(size_t)row * scols + (col - scols)] = fp16out ? f2h(v) : f2b(v);
    }
}

// ---------------- P-GEMM v10: v9 + register double-buffered fragments ----------------
// R2 post-mortem: MFMA-pipe (62%/slot) and LDS-pipe (58%/slot) were ALTERNATING, not
// overlapping — every ds_read fed same-wave MFMAs a few instrs later, and barrier
// lockstep aligned all waves' read phases. Fix: at iter i the wave's operands are
// already in registers (read during i-1); the body issues iter i+1's ds_reads into
// the ALTERNATE register set BEFORE the MFMA cluster, so LDS streams next fragments
// concurrently with the matrix pipe. Static reg sets via 2x-unrolled body (rule #20);
// buffer rotation bc/bn/bs (no modulo); no inline-asm ds_reads (rule #18);
// sched_barrier(0) pins reads between barrier and cluster.
__global__ __launch_bounds__(256, 2)
void k_mfma10(const us* __restrict__ t1b,   // (1024,768) fp16
              const us* __restrict__ W1ct,  // (768,768) fp16 [j][k]
              const us* __restrict__ lb1b,  // (64,768) fp16
              const float* __restrict__ Aw, // (1024,768) f32
              const float* __restrict__ Bc, // (64,768) f32 (includes b1)
              const float* __restrict__ W2, // (768,3) f32
              float* __restrict__ scr) {    // (6,1024,64,3) f32 partials
    __shared__ __align__(16) us As[3][4096];   // [q][row][8] chunk-major, 8 KB per buf
    __shared__ __align__(16) us Bs[3][4096];
    __shared__ __align__(16) us lbs[2][Hd];    // lb1 rows for the 2 labels
    __shared__ float sred[2 * 128 * 3];

    const int tid = threadIdx.x, wave = tid >> 6, lane = tid & 63;
    const int quad = lane >> 4, l15 = lane & 15;
    const int wm = wave & 1, wn = wave >> 1;

    // L2-locality decode: b = xcd + 8*(jx*32 + cp); my = xcd
    const int b = blockIdx.x;
    const int xcd = b & 7, slot = b >> 3;    // slot 0..191
    const int jx = slot >> 5;                // 0..5
    const int cp = slot & 31;                // 0..31 (varies fastest)
    const int c0 = cp * 2;
    const int jt = jx * 128, m0 = xcd * 128;

    for (int i = tid; i < 2 * 128 * 3; i += 256) sred[i] = 0.f;
    if (tid < 192) {                          // stage lb1 rows c0,c0+1 (3 KB)
        int cc = tid / 96, o = (tid - cc * 96) * 8;
        *(short8*)&lbs[cc][o] = *(const short8*)&lb1b[(size_t)(c0 + cc) * Hd + o];
    }

    // staging map: wave issues chunks i=wave and i=wave+4; i -> (q=i>>1, rhalf=i&1)
    const int srow = (wave & 1) * 64 + lane;
    const int skq = (wave >> 1) * 8;          // k offset of chunk q within the 32-k step
    const us* gA = W1ct + (size_t)(jt + srow) * Hd + skq;
    const us* gB = t1b + (size_t)(m0 + srow) * Hd + skq;

    f32x4 acc0[4][4], acc1[4][4];
#pragma unroll
    for (int mt = 0; mt < 4; ++mt)
#pragma unroll
        for (int nt = 0; nt < 4; ++nt) {
            acc0[mt][nt] = (f32x4){0.f, 0.f, 0.f, 0.f};
            acc1[mt][nt] = (f32x4){0.f, 0.f, 0.f, 0.f};
        }

    auto stageT = [&](int p, int k0) {
        gload16(gA + k0,      &As[p][wave * 512]);
        gload16(gA + k0 + 16, &As[p][(wave + 4) * 512]);
        gload16(gB + k0,      &Bs[p][wave * 512]);
        gload16(gB + k0 + 16, &Bs[p][(wave + 4) * 512]);
    };

    // fragment read bases: element (q, row) at us-index q*1024 + row*8
    const int rbA = quad * 1024 + (wm * 64 + l15) * 8;
    const int rbB = quad * 1024 + (wn * 64 + l15) * 8;

    auto readFrags = [&](short8 (&af)[4], short8 (&bf)[4], short8& l0, short8& l1,
                         int buf, int k0) {
        const us* Ab = &As[buf][0];
        const us* Bb = &Bs[buf][0];
#pragma unroll
        for (int mt = 0; mt < 4; ++mt) af[mt] = *(const short8*)&Ab[rbA + mt * 128];
#pragma unroll
        for (int nt = 0; nt < 4; ++nt) bf[nt] = *(const short8*)&Bb[rbB + nt * 128];
        l0 = *(const short8*)&lbs[0][k0 + quad * 8];
        l1 = *(const short8*)&lbs[1][k0 + quad * 8];
    };

    auto cluster = [&](const short8 (&af)[4], const short8 (&bf)[4],
                       const short8& l0, const short8& l1) {
        __builtin_amdgcn_s_setprio(1);
#pragma unroll
        for (int mt = 0; mt < 4; ++mt) {
            short8 a0 = hmul8(af[mt], l0);
            short8 a1 = hmul8(af[mt], l1);
#pragma unroll
            for (int nt = 0; nt < 4; ++nt) {
                acc0[mt][nt] = __builtin_amdgcn_mfma_f32_16x16x32_f16(
                    __builtin_bit_cast(half8, a0),
                    __builtin_bit_cast(half8, bf[nt]), acc0[mt][nt], 0, 0, 0);
                acc1[mt][nt] = __builtin_amdgcn_mfma_f32_16x16x32_f16(
                    __builtin_bit_cast(half8, a1),
                    __builtin_bit_cast(half8, bf[nt]), acc1[mt][nt], 0, 0, 0);
            }
        }
        __builtin_amdgcn_s_setprio(0);
    };

    __syncthreads();        // lbs/sred visible to all waves (nothing in VMEM queue yet)

    stageT(0, 0);
    stageT(1, 32);
    asm volatile("s_waitcnt vmcnt(4)" ::: "memory");   // buf0 staged (buf1's 4 in flight)
    __builtin_amdgcn_s_barrier();
    __builtin_amdgcn_sched_barrier(0);

    short8 afA[4], bfA[4], lvA0, lvA1;
    short8 afB[4], bfB[4], lvB0, lvB1;
    readFrags(afA, bfA, lvA0, lvA1, 0, 0);

    int bc = 0, bn = 1, bs = 2;   // buf holding cur-k / next-k / free(staging)
    for (int i = 0; i < 24; i += 2) {
        // ---- even half: compute set A (k = 32i), read set B (k+32) ----
        if (i + 1 < 24) {
            asm volatile("s_waitcnt vmcnt(0)" ::: "memory");  // bn staged (issued 1 iter ago)
            __builtin_amdgcn_s_barrier();
            __builtin_amdgcn_sched_barrier(0);
            readFrags(afB, bfB, lvB0, lvB1, bn, (i + 1) * 32);
            if (i + 2 < 24) stageT(bs, (i + 2) * 32);
            int t = bc; bc = bn; bn = bs; bs = t;
            __builtin_amdgcn_sched_barrier(0);
        }
        cluster(afA, bfA, lvA0, lvA1);
        // ---- odd half: compute set B (k = 32(i+1)), read set A (k+64) ----
        if (i + 2 < 24) {
            asm volatile("s_waitcnt vmcnt(0)" ::: "memory");
            __builtin_amdgcn_s_barrier();
            __builtin_amdgcn_sched_barrier(0);
            readFrags(afA, bfA, lvA0, lvA1, bn, (i + 2) * 32);
            if (i + 3 < 24) stageT(bs, (i + 3) * 32);
            int t = bc; bc = bn; bn = bs; bs = t;
            __builtin_amdgcn_sched_barrier(0);
        }
        cluster(afB, bfB, lvB0, lvB1);
    }

    // ---- epilogue: per c: h = relu(P + Aw + Bc); sacc[w][r] += h*W2[j][r] ----
    // j = jt + wm*64 + mt*16 + quad*4 + reg ; w = m0 + wn*64 + nt*16 + l15
    float bcv0[4][4], bcv1[4][4], w2v[4][4][3];
#pragma unroll
    for (int mt = 0; mt < 4; ++mt) {
        const int jb = jt + wm * 64 + mt * 16 + quad * 4;
        float4 b4 = *(const float4*)&Bc[(size_t)c0 * Hd + jb];
        bcv0[mt][0] = b4.x; bcv0[mt][1] = b4.y; bcv0[mt][2] = b4.z; bcv0[mt][3] = b4.w;
        float4 b5 = *(const float4*)&Bc[(size_t)(c0 + 1) * Hd + jb];
        bcv1[mt][0] = b5.x; bcv1[mt][1] = b5.y; bcv1[mt][2] = b5.z; bcv1[mt][3] = b5.w;
#pragma unroll
        for (int reg = 0; reg < 4; ++reg)
#pragma unroll
            for (int r = 0; r < 3; ++r) w2v[mt][reg][r] = W2[(jb + reg) * 3 + r];
    }

    auto reduce_c = [&](const f32x4 (&ac)[4][4], const float (&bcv)[4][4], int cc) {
#pragma unroll
        for (int nt = 0; nt < 4; ++nt) {
            const int w = m0 + wn * 64 + nt * 16 + l15;
            const float* awp = Aw + (size_t)w * Hd + jt + wm * 64;
            float s0 = 0.f, s1 = 0.f, s2 = 0.f;
#pragma unroll
            for (int mt = 0; mt < 4; ++mt) {
                float4 a4 = *(const float4*)&awp[mt * 16 + quad * 4];
                float av[4] = {a4.x, a4.y, a4.z, a4.w};
#pragma unroll
                for (int reg = 0; reg < 4; ++reg) {
                    float h = ac[mt][nt][reg] + av[reg] + bcv[mt][reg];
                    h = h > 0.f ? h : 0.f;
                    s0 += h * w2v[mt][reg][0];
                    s1 += h * w2v[mt][reg][1];
                    s2 += h * w2v[mt][reg][2];
                }
            }
            s0 += __shfl_xor(s0, 16); s0 += __shfl_xor(s0, 32);
            s1 += __shfl_xor(s1, 16); s1 += __shfl_xor(s1, 32);
            s2 += __shfl_xor(s2, 16); s2 += __shfl_xor(s2, 32);
            if (quad == 0) {
                const int wl = wn * 64 + nt * 16 + l15;
                atomicAdd(&sred[cc * 384 + wl * 3 + 0], s0);   // LDS, 2-way (wm)
                atomicAdd(&sred[cc * 384 + wl * 3 + 1], s1);
                atomicAdd(&sred[cc * 384 + wl * 3 + 2], s2);
            }
        }
    };
    reduce_c(acc0, bcv0, 0);
    reduce_c(acc1, bcv1, 1);
    __syncthreads();

    // non-atomic store to per-jx scratch slot (disjoint across blocks)
    float* slab = scr + ((size_t)jx * 1024 * Cn + (size_t)m0 * Cn) * 3;
    for (int i = tid; i < 2 * 128 * 3; i += 256) {
        int cc = i / 384, j = i - cc * 384;
        int wl = j / 3, r = j - wl * 3;
        slab[((size_t)wl * Cn + (c0 + cc)) * 3 + r] = sred[i];
    }
}

// ---------- final: out = b2 + sum_jx scr[jx] ----------
__global__ __launch_bounds__(256)
void k_scores(const float* __restrict__ scr, const float* __restrict__ b2,
              float* __restrict__ out, int n) {
    int i = blockIdx.x * 256 + threadIdx.x;
    if (i >= n) return;
    float v = b2[i % 3];
#pragma unroll
    for (int s = 0; s < 6; ++s) v += scr[(size_t)s * n + i];
    out[i] = v;
}

extern "C" void kernel_launch(void* const* d_in, const int* in_sizes, int n_in,
                              void* d_out, int out_size, void* d_ws, size_t ws_size,
                              hipStream_t stream) {
    const float* tok    = (const float*)d_in[0];
    const int*   wmask  = (const int*)d_in[1];
    const float* labe   = (const float*)d_in[3];
    const float* W_tok  = (const float*)d_in[4];
    const float* b_tok  = (const float*)d_in[5];
    const float* W_lab  = (const float*)d_in[6];
    const float* b_lab  = (const float*)d_in[7];
    const float* W1     = (const float*)d_in[8];
    const float* b1     = (const float*)d_in[9];
    const float* W2     = (const float*)d_in[10];
    const float* b2     = (const float*)d_in[11];
    float* out = (float*)d_out;

    const int L  = in_sizes[1];
    const int Wd = out_size / (Cn * 3);   // 1024

    char* ws = (char*)d_ws;
    size_t off = 0;
    auto alloc = [&](size_t bytes) { char* p = ws + off; off += (bytes + 255) & ~(size_t)255; return p; };
    // ---- persistent region ----
    int*   widx  = (int*)alloc(4096);
    float* Abuf  = (float*)alloc((size_t)Wd * Hd * 4);
    float* Bbuf  = (float*)alloc((size_t)Cn * Hd * 4);
    us* W1ct  = (us*)alloc((size_t)Hd * Hd * 2);   // fp16
    us* W1cl  = (us*)alloc((size_t)Hd * Hd * 2);   // unused
    us* t1b   = (us*)alloc((size_t)Wd * Hd * 2);   // fp16
    us* lb1b  = (us*)alloc((size_t)Cn * Hd * 2);   // fp16
    float* scr = (float*)alloc((size_t)6 * Wd * Cn * 3 * 4);   // 4.72 MB partials
    // ---- scratch region ----
    us* WtTh  = (us*)alloc((size_t)H2 * Hd * 2);
    us* WtTl  = (us*)alloc((size_t)H2 * Hd * 2);
    us* WlTh  = (us*)alloc((size_t)H2 * Hd * 2);
    us* WlTl  = (us*)alloc((size_t)H2 * Hd * 2);
    us* W1aTh = (us*)alloc((size_t)Hd * Hd * 2);
    us* W1aTl = (us*)alloc((size_t)Hd * Hd * 2);
    us* W1bTh = (us*)alloc((size_t)Hd * Hd * 2);
    us* W1bTl = (us*)alloc((size_t)Hd * Hd * 2);
    us* weh   = (us*)alloc((size_t)Wd * Hd * 2);
    us* wel   = (us*)alloc((size_t)Wd * Hd * 2);
    us* lah   = (us*)alloc((size_t)Cn * Hd * 2);
    us* lal   = (us*)alloc((size_t)Cn * Hd * 2);
    us* t0h   = (us*)alloc((size_t)Wd * Hd * 2);
    us* t0l   = (us*)alloc((size_t)Wd * Hd * 2);
    us* lb0h  = (us*)alloc((size_t)Cn * Hd * 2);
    us* lb0l  = (us*)alloc((size_t)Cn * Hd * 2);
    float* part = (float*)alloc((size_t)8 * Cn * H2 * 4);

    // 1) init + scatter + we split
    k_init<<<(Wd + 255) / 256, 256, 0, stream>>>(widx, Wd);
    k_scatter<<<(L + 255) / 256, 256, 0, stream>>>(wmask, widx, L, Wd);
    k_build_we_split<<<(Wd * 192 + 255) / 256, 256, 0, stream>>>((const float4*)tok, widx, weh, wel, Wd);

    // 2) batched weight transpose+split (W1c -> fp16)
    TSArgs ts;
    ts.src[0] = W_tok;  ts.th[0] = WtTh;  ts.tl[0] = WtTl;  ts.ld[0] = H2; ts.N[0] = H2; ts.fmt[0] = 0;
    ts.src[1] = W_lab;  ts.th[1] = WlTh;  ts.tl[1] = WlTl;  ts.ld[1] = H2; ts.N[1] = H2; ts.fmt[1] = 0;
    ts.src[2] = W1;                         ts.th[2] = W1aTh; ts.tl[2] = W1aTl; ts.ld[2] = Hd; ts.N[2] = Hd; ts.fmt[2] = 0;
    ts.src[3] = W1 + (size_t)Hd * Hd;       ts.th[3] = W1bTh; ts.tl[3] = W1bTl; ts.ld[3] = Hd; ts.N[3] = Hd; ts.fmt[3] = 0;
    ts.src[4] = W1 + (size_t)2 * Hd * Hd;   ts.th[4] = W1ct;  ts.tl[4] = W1cl;  ts.ld[4] = Hd; ts.N[4] = Hd; ts.fmt[4] = 1;
    k_tsplit<<<dim3(H2 / 64, Hd / 64, 5), 256, 0, stream>>>(ts);

    // 3) label emb split
    k_split<<<(Cn * Hd / 4 + 255) / 256, 256, 0, stream>>>(labe, Hd, Hd, lah, lal, Cn * Hd / 4);

    // 4) t = we @ W_tok + b_tok -> fused t0 hi/lo + t1b fp16
    k_gemm3<<<dim3(H2 / 64, Wd / 64), 256, 0, stream>>>(weh, wel, WtTh, WtTl, b_tok,
                                                        nullptr, t0h, t0l, t1b, 1, Hd, H2, Hd);

    // 5) lb = labe @ W_lab + b_lab (64x1536), z=8 -> reduce (lb0 split + lb1b fp16)
    k_gemm2<<<dim3(H2 / 64, 1, 8), 256, 0, stream>>>(lah, lal, WlTh, WlTl, part, Cn, H2, Hd);
    k_reduce<<<(Cn * H2 + 255) / 256, 256, 0, stream>>>(part, 8, Cn * H2, H2, b_lab, nullptr, lb0h, lb0l, Hd, lb1b, 1);

    // 6) Aw = t0 @ W1a (1024x768) -> fused f32 write
    k_gemm3<<<dim3(Hd / 64, Wd / 64), 256, 0, stream>>>(t0h, t0l, W1aTh, W1aTl, nullptr,
                                                        Abuf, nullptr, nullptr, nullptr, 0, 0, Hd, Hd);

    // 7) Bc = lb0 @ W1b + b1 (64x768), z=8 -> reduce
    k_gemm2<<<dim3(Hd / 64, 1, 8), 256, 0, stream>>>(lb0h, lb0l, W1bTh, W1bTl, part, Cn, Hd, Hd);
    k_reduce<<<(Cn * Hd + 255) / 256, 256, 0, stream>>>(part, 8, Cn * Hd, Hd, b1, Bbuf, nullptr, nullptr, Hd, nullptr, 0);

    // 8) fused fp16 P-GEMM v10 (reg double-buffered fragments) -> scratch
    k_mfma10<<<1536, 256, 0, stream>>>(t1b, W1ct, lb1b, Abuf, Bbuf, W2, scr);

    // 9) out = b2 + sum_jx scr
    k_scores<<<(Wd * Cn * 3 + 255) / 256, 256, 0, stream>>>(scr, b2, out, Wd * Cn * 3);
}